// Round 6
// baseline (1859.396 us; speedup 1.0000x reference)
//
#include <hip/hip_runtime.h>
#include <stdint.h>
#include <stddef.h>

// ---------------------------------------------------------------------------
// Sparse top-2 MoE, bf16 MFMA, fp32 accumulate.
//   convert: w1/w3/w2 fp32 -> bf16, tile-panel layout [e][p][q][128x64],
//            XOR-swizzled (chunk cs holds logical col cs^(r&7))
//   router:  logits -> softmax -> top2 -> per-expert compact lists (+x->bf16)
//   GU:      h = silu(x@w1^T) * (x@w3^T)  256x128 dbuf, counted-vmcnt deep pipe
//   Y:       out += coef * (h@w2^T)       256x128 tri-buf, distance-2 prefetch
// Dispatch is nt-major (PROVEN round 2/3): consecutive blocks share the
// weight panel (L2-hit); A (xb 32 MB / hbuf 128 MB) re-reads are L3-resident.
// (Round-4 mt-major regressed: per-block distinct weight panels -> HBM
//  latency-bound, + partial-cacheline RMW on hbuf writes.)
// ws layout (MiB): [0,1) lists | [1,33) xb | [33,161) w1b (later w2b)
//                  [161,289) w3b | [289,418) hbuf
// ---------------------------------------------------------------------------

constexpr int kTokens  = 8192;
constexpr int kHidden  = 2048;
constexpr int kInter   = 4096;
constexpr int kExperts = 8;

constexpr int BM = 128, BN = 128, BK = 64;              // fallback tile
constexpr int MAX_MT = (2 * kTokens) / BM + kExperts;   // 136

constexpr int BM2 = 256, BN2 = 128;                     // main tile
constexpr int MAX_MT2 = (2 * kTokens) / BM2 + kExperts; // 72
constexpr int NT2 = kHidden / BK;                       // 32 K-tiles (GU)
constexpr int NTY = kInter / BK;                        // 64 K-tiles (Y)
constexpr int NPAN_GU = kInter / BN2;                   // 32 B panels
constexpr int NPAN_Y  = kHidden / BN2;                  // 16 B panels
constexpr int kSlotCap = 16512;                         // hbuf rows incl. slack

typedef short bf16x8 __attribute__((ext_vector_type(8)));
typedef float f32x4  __attribute__((ext_vector_type(4)));
typedef unsigned int u32;

__device__ __forceinline__ unsigned short f2bf(float f) {
  union { float f; unsigned u; } v; v.f = f;
  unsigned r = v.u + 0x7FFFu + ((v.u >> 16) & 1u);  // RTNE
  return (unsigned short)(r >> 16);
}

__device__ __forceinline__ void gload16(const void* g, void* l) {
  __builtin_amdgcn_global_load_lds(
      (const __attribute__((address_space(1))) u32*)g,
      (__attribute__((address_space(3))) u32*)l, 16, 0, 0);
}

// ---------------------------- weight convert ----------------------------
__global__ __launch_bounds__(256) void convert_w(
    const float* __restrict__ src, unsigned short* __restrict__ dst,
    int lp, int lq, int K, long nchunks)
{
  long stride = (long)gridDim.x * blockDim.x;
  for (long g = blockIdx.x * (long)blockDim.x + threadIdx.x; g < nchunks; g += stride) {
    int  l   = (int)(g & 1023);
    long blk = g >> 10;
    int  q   = (int)(blk & ((1 << lq) - 1));
    long ep  = blk >> lq;
    int  p   = (int)(ep & ((1 << lp) - 1));
    int  e   = (int)(ep >> lp);
    int r = l >> 3, cs = l & 7, c = cs ^ (r & 7);
    size_t soff = (((size_t)(e << lp) + p) * 128 + r) * (size_t)K + (size_t)q * 64 + c * 8;
    float4 v0 = *reinterpret_cast<const float4*>(src + soff);
    float4 v1 = *reinterpret_cast<const float4*>(src + soff + 4);
    uint4 o;
    o.x = (u32)f2bf(v0.x) | ((u32)f2bf(v0.y) << 16);
    o.y = (u32)f2bf(v0.z) | ((u32)f2bf(v0.w) << 16);
    o.z = (u32)f2bf(v1.x) | ((u32)f2bf(v1.y) << 16);
    o.w = (u32)f2bf(v1.z) | ((u32)f2bf(v1.w) << 16);
    *reinterpret_cast<uint4*>(dst + g * 8) = o;
  }
}

// ---------------------------- router ----------------------------
__global__ __launch_bounds__(256) void moe_router(
    const float* __restrict__ x, const float* __restrict__ gate_w,
    unsigned short* __restrict__ xb, int* __restrict__ counts,
    int* __restrict__ list_idx, float* __restrict__ list_w)
{
  const int lane = threadIdx.x & 63;
  const int wave = threadIdx.x >> 6;
  const int t = blockIdx.x * 4 + wave;

  float acc[kExperts];
#pragma unroll
  for (int e = 0; e < kExperts; ++e) acc[e] = 0.f;

  const float4* xrow = reinterpret_cast<const float4*>(x + (size_t)t * kHidden);
#pragma unroll
  for (int j = 0; j < 8; ++j) {
    float4 xv = xrow[j * 64 + lane];
    uint2 pk;
    pk.x = (u32)f2bf(xv.x) | ((u32)f2bf(xv.y) << 16);
    pk.y = (u32)f2bf(xv.z) | ((u32)f2bf(xv.w) << 16);
    *reinterpret_cast<uint2*>(xb + (size_t)t * kHidden + j * 256 + lane * 4) = pk;
#pragma unroll
    for (int e = 0; e < kExperts; ++e) {
      float4 gv = reinterpret_cast<const float4*>(gate_w + (size_t)e * kHidden)[j * 64 + lane];
      acc[e] += xv.x * gv.x + xv.y * gv.y + xv.z * gv.z + xv.w * gv.w;
    }
  }
#pragma unroll
  for (int e = 0; e < kExperts; ++e) {
#pragma unroll
    for (int m = 32; m >= 1; m >>= 1) acc[e] += __shfl_xor(acc[e], m);
  }
  if (lane == 0) {
    float mx = acc[0];
#pragma unroll
    for (int e = 1; e < kExperts; ++e) mx = fmaxf(mx, acc[e]);
    float p[kExperts]; float s = 0.f;
#pragma unroll
    for (int e = 0; e < kExperts; ++e) { p[e] = __expf(acc[e] - mx); s += p[e]; }
    float inv = 1.f / s;
    int i1 = 0; float v1 = p[0];
#pragma unroll
    for (int e = 1; e < kExperts; ++e) if (p[e] > v1) { v1 = p[e]; i1 = e; }
    int i2 = (i1 == 0) ? 1 : 0; float v2 = p[i2];
#pragma unroll
    for (int e = 0; e < kExperts; ++e) {
      if (e == i1 || e == i2) continue;
      if (p[e] > v2) { v2 = p[e]; i2 = e; }
    }
    int s1 = atomicAdd(&counts[i1], 1);
    list_idx[i1 * kTokens + s1] = t;
    list_w [i1 * kTokens + s1] = v1 * inv;
    int s2 = atomicAdd(&counts[i2], 1);
    list_idx[i2 * kTokens + s2] = t;
    list_w [i2 * kTokens + s2] = v2 * inv;
  }
}

// ------------------- tile mapping helpers -------------------
__device__ __forceinline__ bool map_tile(const int* __restrict__ counts, int mt,
                                         int& e, int& lm, int& sb, int& ne)
{
  int tb = 0; sb = 0;
  for (e = 0; e < kExperts; ++e) {
    ne = counts[e];
    int tiles = (ne + BM - 1) / BM;
    if (mt < tb + tiles) { lm = mt - tb; return true; }
    tb += tiles; sb += ne;
  }
  return false;
}

__device__ __forceinline__ bool map_tile2(const int* __restrict__ counts, int mt,
                                          int& e, int& lm, int& sb, int& ne)
{
  int tb = 0; sb = 0;
  for (e = 0; e < kExperts; ++e) {
    ne = counts[e];
    int tiles = (ne + BM2 - 1) / BM2;
    if (mt < tb + tiles) { lm = mt - tb; return true; }
    tb += tiles; sb += ne;
  }
  return false;
}

// ------------- GU GEMM: deep counted-vmcnt double-buffer pipeline -------------
// Units per K-tile: A0,A1 (token-row halves, wave wr reads unit wr), B1, B3.
// Issue(next): A0,A1 early-R0; B1 late-R0; B3 in R1.
// Waits: vmcnt(6) end-R0 (forces B3(t), 4-phase cover);
//        vmcnt(2) end-R1 (forces A0,A1,B1(t+1), 3-4 phase cover).
__global__ __launch_bounds__(512, 2) void moe_gu2(
    const unsigned short* __restrict__ xb,
    const unsigned short* __restrict__ w1b, const unsigned short* __restrict__ w3b,
    const int* __restrict__ counts, const int* __restrict__ list_idx,
    unsigned short* __restrict__ hbuf)
{
  // shorts: A[b][h] at (b*2+h)*8192 | B1[b] at 32768+b*8192 | B3[b] at 49152+b*8192
  __shared__ unsigned short lds[65536];
  __shared__ int toks[BM2];

  const int tid = threadIdx.x;
  const int nt  = blockIdx.x / MAX_MT2;   // nt-major: co-resident blocks share B
  const int mt  = blockIdx.x % MAX_MT2;

  int e, lm, sb, ne;
  if (!map_tile2(counts, mt, e, lm, sb, ne)) return;
  const int row0 = lm * BM2;

  if (tid < BM2) {
    int lr = row0 + tid;
    toks[tid] = list_idx[e * kTokens + ((lr < ne) ? lr : 0)];
  }
  __syncthreads();

  const int lane = tid & 63;
  const int w    = tid >> 6;
  const int wr   = w >> 2;   // 0..1 : which 128-row half of A
  const int wc   = w & 3;    // 0..3 : which 32-col slice of B

  const unsigned short* srcA[2][2];
  const unsigned short* srcB1[2];
  const unsigned short* srcB3[2];
  {
    const size_t bb = ((size_t)(e * NPAN_GU + nt) * NT2) * 1024;
#pragma unroll
    for (int i = 0; i < 2; ++i) {
      int l = (w * 2 + i) * 64 + lane;
      int r = l >> 3, cs = l & 7, c = cs ^ (r & 7);
#pragma unroll
      for (int h = 0; h < 2; ++h)
        srcA[h][i] = xb + (size_t)toks[h * 128 + r] * kHidden + c * 8;
      srcB1[i] = w1b + (bb + l) * 8;
      srcB3[i] = w3b + (bb + l) * 8;
    }
  }

  f32x4 accG[8][2], accU[8][2];
  const f32x4 zero = {0.f, 0.f, 0.f, 0.f};
#pragma unroll
  for (int m = 0; m < 8; ++m)
#pragma unroll
    for (int n = 0; n < 2; ++n) { accG[m][n] = zero; accU[m][n] = zero; }

  // prologue: stage tile 0 into buf0; order A0,A1,B1,B3 (matches loop issue order)
#pragma unroll
  for (int i = 0; i < 2; ++i) gload16(srcA[0][i], &lds[0 * 8192 + (w * 2 + i) * 512]);
#pragma unroll
  for (int i = 0; i < 2; ++i) gload16(srcA[1][i], &lds[1 * 8192 + (w * 2 + i) * 512]);
#pragma unroll
  for (int i = 0; i < 2; ++i) gload16(srcB1[i], &lds[32768 + (w * 2 + i) * 512]);
#pragma unroll
  for (int i = 0; i < 2; ++i) gload16(srcB3[i], &lds[49152 + (w * 2 + i) * 512]);
  asm volatile("s_waitcnt vmcnt(2)" ::: "memory");  // A0,A1,B1 of tile 0 resident
  __builtin_amdgcn_sched_barrier(0);
  __builtin_amdgcn_s_barrier();

  for (int t2 = 0; t2 < NT2; t2 += 2) {
#pragma unroll
    for (int u = 0; u < 2; ++u) {
      const int t  = t2 + u;
      const int cb = u, nb = u ^ 1;
      const int tn = (t + 1 < NT2) ? (t + 1) : (NT2 - 1);  // dummy re-stage on last
      const int Acur = (cb * 2 + wr) * 8192;
      const int B1c  = 32768 + cb * 8192;
      const int B3c  = 49152 + cb * 8192;
      const int An0  = (nb * 2 + 0) * 8192;
      const int An1  = (nb * 2 + 1) * 8192;
      const int B1n  = 32768 + nb * 8192;
      const int B3n  = 49152 + nb * 8192;

      bf16x8 a0[4][2], a1[4][2], b1f[2][2], b3f[2][2];

      // =================== region 0: G = x @ w1^T ===================
#pragma unroll
      for (int m = 0; m < 4; ++m) {
        const int r = m * 16 + (lane & 15);
#pragma unroll
        for (int kk = 0; kk < 2; ++kk) {
          const int cq = kk * 4 + (lane >> 4);
          a0[m][kk] = *reinterpret_cast<const bf16x8*>(&lds[Acur + r * 64 + ((cq ^ (r & 7)) << 3)]);
        }
      }
#pragma unroll
      for (int n = 0; n < 2; ++n) {
        const int r = wc * 32 + n * 16 + (lane & 15);
#pragma unroll
        for (int kk = 0; kk < 2; ++kk) {
          const int cq = kk * 4 + (lane >> 4);
          b1f[n][kk] = *reinterpret_cast<const bf16x8*>(&lds[B1c + r * 64 + ((cq ^ (r & 7)) << 3)]);
        }
      }
#pragma unroll
      for (int i = 0; i < 2; ++i) {
        gload16(srcA[0][i] + tn * BK, &lds[An0 + (w * 2 + i) * 512]);
        gload16(srcA[1][i] + tn * BK, &lds[An1 + (w * 2 + i) * 512]);
      }
      __builtin_amdgcn_s_setprio(1);
#pragma unroll
      for (int m = 0; m < 4; ++m)
#pragma unroll
        for (int n = 0; n < 2; ++n)
#pragma unroll
          for (int kk = 0; kk < 2; ++kk)
            accG[m][n] = __builtin_amdgcn_mfma_f32_16x16x32_bf16(a0[m][kk], b1f[n][kk], accG[m][n], 0, 0, 0);
      __builtin_amdgcn_s_setprio(0);
      __builtin_amdgcn_sched_barrier(0);

#pragma unroll
      for (int m = 0; m < 4; ++m) {
        const int r = 64 + m * 16 + (lane & 15);
#pragma unroll
        for (int kk = 0; kk < 2; ++kk) {
          const int cq = kk * 4 + (lane >> 4);
          a1[m][kk] = *reinterpret_cast<const bf16x8*>(&lds[Acur + r * 64 + ((cq ^ (r & 7)) << 3)]);
        }
      }
#pragma unroll
      for (int i = 0; i < 2; ++i)
        gload16(srcB1[i] + (size_t)tn * 8192, &lds[B1n + (w * 2 + i) * 512]);
      __builtin_amdgcn_s_setprio(1);
#pragma unroll
      for (int m = 0; m < 4; ++m)
#pragma unroll
        for (int n = 0; n < 2; ++n)
#pragma unroll
          for (int kk = 0; kk < 2; ++kk)
            accG[4 + m][n] = __builtin_amdgcn_mfma_f32_16x16x32_bf16(a1[m][kk], b1f[n][kk], accG[4 + m][n], 0, 0, 0);
      __builtin_amdgcn_s_setprio(0);
      __builtin_amdgcn_sched_barrier(0);
      asm volatile("s_waitcnt vmcnt(6)" ::: "memory");  // forces B3(t)
      __builtin_amdgcn_s_barrier();

      // =================== region 1: U = x @ w3^T ===================
#pragma unroll
      for (int n = 0; n < 2; ++n) {
        const int r = wc * 32 + n * 16 + (lane & 15);
#pragma unroll
        for (int kk = 0; kk < 2; ++kk) {
          const int cq = kk * 4 + (lane >> 4);
          b3f[n][kk] = *reinterpret_cast<const bf16x8*>(&lds[B3c + r * 64 + ((cq ^ (r & 7)) << 3)]);
        }
      }
#pragma unroll
      for (int i = 0; i < 2; ++i)
        gload16(srcB3[i] + (size_t)tn * 8192, &lds[B3n + (w * 2 + i) * 512]);
      __builtin_amdgcn_s_setprio(1);
#pragma unroll
      for (int m = 0; m < 4; ++m)
#pragma unroll
        for (int n = 0; n < 2; ++n)
#pragma unroll
          for (int kk = 0; kk < 2; ++kk)
            accU[m][n] = __builtin_amdgcn_mfma_f32_16x16x32_bf16(a0[m][kk], b3f[n][kk], accU[m][n], 0, 0, 0);
      __builtin_amdgcn_s_setprio(0);
      __builtin_amdgcn_sched_barrier(0);
      __builtin_amdgcn_s_setprio(1);
#pragma unroll
      for (int m = 0; m < 4; ++m)
#pragma unroll
        for (int n = 0; n < 2; ++n)
#pragma unroll
          for (int kk = 0; kk < 2; ++kk)
            accU[4 + m][n] = __builtin_amdgcn_mfma_f32_16x16x32_bf16(a1[m][kk], b3f[n][kk], accU[4 + m][n], 0, 0, 0);
      __builtin_amdgcn_s_setprio(0);
      __builtin_amdgcn_sched_barrier(0);
      asm volatile("s_waitcnt vmcnt(2)" ::: "memory");  // forces A0,A1,B1(t+1)
      __builtin_amdgcn_s_barrier();
    }
  }

  // epilogue: h = silu(g)*u
#pragma unroll
  for (int am = 0; am < 8; ++am) {
#pragma unroll
    for (int r = 0; r < 4; ++r) {
      int rloc = wr * 128 + am * 16 + ((lane >> 4) * 4) + r;
      int lrow = row0 + rloc;
      if (lrow < ne) {
        size_t base = (size_t)(sb + lrow) * kInter + (size_t)nt * BN2 + wc * 32 + (lane & 15);
#pragma unroll
        for (int n = 0; n < 2; ++n) {
          float g = accG[am][n][r];
          float u = accU[am][n][r];
          float hv = (g / (1.f + __expf(-g))) * u;
          hbuf[base + n * 16] = f2bf(hv);
        }
      }
    }
  }
}

// ------------- Y GEMM: tri-buffer distance-2 prefetch pipeline -------------
// Buffer (shorts): [Ah0 8192][Ah1 8192][B 8192] x 3.
// Issue during tile t (for t+2): A0,B early; A1 late. One wait per tile:
// vmcnt(6) end-tile forces all of tile t+1 (3-4 phase cover).
#define Y_TILE(T, CB)                                                          \
  {                                                                            \
    const int tn  = ((T) + 2 < NTY) ? ((T) + 2) : (NTY - 1);                   \
    const int cob = (CB) * 24576;                                              \
    const int nxb = (((CB) + 2) % 3) * 24576;                                  \
    bf16x8 a0[4][2], a1[4][2], bfv[2][2];                                      \
    _Pragma("unroll")                                                          \
    for (int m = 0; m < 4; ++m) {                                              \
      const int r = m * 16 + (lane & 15);                                      \
      _Pragma("unroll")                                                        \
      for (int kk = 0; kk < 2; ++kk) {                                         \
        const int cq = kk * 4 + (lane >> 4);                                   \
        a0[m][kk] = *reinterpret_cast<const bf16x8*>(                          \
            &lds[cob + wr * 8192 + r * 64 + ((cq ^ (r & 7)) << 3)]);           \
      }                                                                        \
    }                                                                          \
    _Pragma("unroll")                                                          \
    for (int n = 0; n < 2; ++n) {                                              \
      const int r = wc * 32 + n * 16 + (lane & 15);                            \
      _Pragma("unroll")                                                        \
      for (int kk = 0; kk < 2; ++kk) {                                         \
        const int cq = kk * 4 + (lane >> 4);                                   \
        bfv[n][kk] = *reinterpret_cast<const bf16x8*>(                         \
            &lds[cob + 16384 + r * 64 + ((cq ^ (r & 7)) << 3)]);               \
      }                                                                        \
    }                                                                          \
    _Pragma("unroll")                                                          \
    for (int i = 0; i < 2; ++i) {                                              \
      gload16(srcA[0][i] + (size_t)tn * BK, &lds[nxb + (w * 2 + i) * 512]);    \
      gload16(srcB[i] + (size_t)tn * 8192, &lds[nxb + 16384 + (w * 2 + i) * 512]); \
    }                                                                          \
    __builtin_amdgcn_s_setprio(1);                                             \
    _Pragma("unroll")                                                          \
    for (int m = 0; m < 4; ++m)                                                \
      _Pragma("unroll")                                                        \
      for (int n = 0; n < 2; ++n)                                              \
        _Pragma("unroll")                                                      \
        for (int kk = 0; kk < 2; ++kk)                                         \
          acc[m][n] = __builtin_amdgcn_mfma_f32_16x16x32_bf16(a0[m][kk], bfv[n][kk], acc[m][n], 0, 0, 0); \
    __builtin_amdgcn_s_setprio(0);                                             \
    __builtin_amdgcn_sched_barrier(0);                                         \
    _Pragma("unroll")                                                          \
    for (int m = 0; m < 4; ++m) {                                              \
      const int r = 64 + m * 16 + (lane & 15);                                 \
      _Pragma("unroll")                                                        \
      for (int kk = 0; kk < 2; ++kk) {                                         \
        const int cq = kk * 4 + (lane >> 4);                                   \
        a1[m][kk] = *reinterpret_cast<const bf16x8*>(                          \
            &lds[cob + wr * 8192 + r * 64 + ((cq ^ (r & 7)) << 3)]);           \
      }                                                                        \
    }                                                                          \
    _Pragma("unroll")                                                          \
    for (int i = 0; i < 2; ++i)                                                \
      gload16(srcA[1][i] + (size_t)tn * BK, &lds[nxb + 8192 + (w * 2 + i) * 512]); \
    __builtin_amdgcn_s_setprio(1);                                             \
    _Pragma("unroll")                                                          \
    for (int m = 0; m < 4; ++m)                                                \
      _Pragma("unroll")                                                        \
      for (int n = 0; n < 2; ++n)                                              \
        _Pragma("unroll")                                                      \
        for (int kk = 0; kk < 2; ++kk)                                         \
          acc[4 + m][n] = __builtin_amdgcn_mfma_f32_16x16x32_bf16(a1[m][kk], bfv[n][kk], acc[4 + m][n], 0, 0, 0); \
    __builtin_amdgcn_s_setprio(0);                                             \
    __builtin_amdgcn_sched_barrier(0);                                         \
    asm volatile("s_waitcnt vmcnt(6)" ::: "memory");                           \
    __builtin_amdgcn_s_barrier();                                              \
  }

__global__ __launch_bounds__(512, 2) void moe_y2(
    const unsigned short* __restrict__ hbuf,
    const unsigned short* __restrict__ w2b,
    const int* __restrict__ counts, const int* __restrict__ list_idx,
    const float* __restrict__ list_w,
    float* __restrict__ out)
{
  __shared__ unsigned short lds[73728];  // 3 x 48 KiB buffers
  __shared__ int   toks[BM2];
  __shared__ float cofs[BM2];

  const int tid = threadIdx.x;
  const int nt  = blockIdx.x / MAX_MT2;   // nt-major: co-resident blocks share B
  const int mt  = blockIdx.x % MAX_MT2;

  int e, lm, sb, ne;
  if (!map_tile2(counts, mt, e, lm, sb, ne)) return;
  const int row0 = lm * BM2;

  if (tid < BM2) {
    int lr = row0 + tid;
    bool v = lr < ne;
    toks[tid] = v ? list_idx[e * kTokens + lr] : 0;
    cofs[tid] = v ? list_w [e * kTokens + lr] : 0.f;
  }
  __syncthreads();

  const int lane = tid & 63;
  const int w    = tid >> 6;
  const int wr   = w >> 2;
  const int wc   = w & 3;

  const unsigned short* srcA[2][2];
  const unsigned short* srcB[2];
  {
    const size_t bb = ((size_t)(e * NPAN_Y + nt) * NTY) * 1024;
#pragma unroll
    for (int i = 0; i < 2; ++i) {
      int l = (w * 2 + i) * 64 + lane;
      int r = l >> 3, cs = l & 7, c = cs ^ (r & 7);
#pragma unroll
      for (int h = 0; h < 2; ++h) {
        int rg = sb + row0 + h * 128 + r;
        if (rg > kSlotCap - 1) rg = kSlotCap - 1;   // clamp into hbuf slack
        srcA[h][i] = hbuf + (size_t)rg * kInter + c * 8;
      }
      srcB[i] = w2b + (bb + l) * 8;
    }
  }

  f32x4 acc[8][2];
  const f32x4 zero = {0.f, 0.f, 0.f, 0.f};
#pragma unroll
  for (int m = 0; m < 8; ++m)
#pragma unroll
    for (int n = 0; n < 2; ++n) acc[m][n] = zero;

  // prologue: tiles 0,1 -> bufs 0,1; per-tile order A0,B,A1 (matches loop)
#pragma unroll
  for (int t = 0; t < 2; ++t) {
    const int bo = t * 24576;
#pragma unroll
    for (int i = 0; i < 2; ++i) {
      gload16(srcA[0][i] + (size_t)t * BK, &lds[bo + (w * 2 + i) * 512]);
      gload16(srcB[i] + (size_t)t * 8192, &lds[bo + 16384 + (w * 2 + i) * 512]);
    }
#pragma unroll
    for (int i = 0; i < 2; ++i)
      gload16(srcA[1][i] + (size_t)t * BK, &lds[bo + 8192 + (w * 2 + i) * 512]);
  }
  asm volatile("s_waitcnt vmcnt(6)" ::: "memory");  // tile 0 resident
  __builtin_amdgcn_sched_barrier(0);
  __builtin_amdgcn_s_barrier();

  Y_TILE(0, 0)
  for (int t3 = 1; t3 < NTY; t3 += 3) {   // 1..63 in 21 triples; 63%3==0 ends cb cycle
    Y_TILE(t3, 1)
    Y_TILE(t3 + 1, 2)
    Y_TILE(t3 + 2, 0)
  }

  // epilogue: out[token] += coef * y
#pragma unroll
  for (int am = 0; am < 8; ++am) {
#pragma unroll
    for (int r = 0; r < 4; ++r) {
      int rloc = wr * 128 + am * 16 + ((lane >> 4) * 4) + r;
      if (row0 + rloc < ne) {
        float cf = cofs[rloc];
        size_t obase = (size_t)toks[rloc] * kHidden + (size_t)nt * BN2 + wc * 32 + (lane & 15);
#pragma unroll
        for (int n = 0; n < 2; ++n)
          atomicAdd(&out[obase + n * 16], cf * acc[am][n][r]);
      }
    }
  }
}

// ===================== fallback (fp32 on-the-fly) ============
__global__ __launch_bounds__(256, 2) void moe_gu_f32(
    const unsigned short* __restrict__ xb,
    const float* __restrict__ w1, const float* __restrict__ w3,
    const int* __restrict__ counts, const int* __restrict__ list_idx,
    unsigned short* __restrict__ hbuf)
{
  __shared__ unsigned short As [BM * BK];
  __shared__ unsigned short B1s[BN * BK];
  __shared__ unsigned short B3s[BN * BK];
  __shared__ int toks[BM];

  const int tid = threadIdx.x;
  const int nt  = blockIdx.x / MAX_MT;
  const int mt  = blockIdx.x % MAX_MT;

  int e, lm, sb, ne;
  if (!map_tile(counts, mt, e, lm, sb, ne)) return;
  const int row0 = lm * BM;

  if (tid < BM) {
    int lr = row0 + tid;
    toks[tid] = list_idx[e * kTokens + ((lr < ne) ? lr : 0)];
  }
  __syncthreads();

  const unsigned short* aptr[4];
#pragma unroll
  for (int i = 0; i < 4; ++i) {
    int chunk = i * 256 + tid;
    int r = chunk >> 3, c8 = chunk & 7;
    aptr[i] = xb + (size_t)toks[r] * kHidden + c8 * 8;
  }
  const float* w1e = w1 + (size_t)e * kInter * kHidden;
  const float* w3e = w3 + (size_t)e * kInter * kHidden;

  f32x4 accG[4][4], accU[4][4];
  const f32x4 zero = {0.f, 0.f, 0.f, 0.f};
#pragma unroll
  for (int m = 0; m < 4; ++m)
#pragma unroll
    for (int n = 0; n < 4; ++n) { accG[m][n] = zero; accU[m][n] = zero; }

  const int lane = tid & 63;
  const int wr = (tid >> 6) >> 1;
  const int wc = (tid >> 6) & 1;

  for (int k0 = 0; k0 < kHidden; k0 += BK) {
#pragma unroll
    for (int i = 0; i < 4; ++i) {
      int chunk = i * 256 + tid;
      uint4 v = *reinterpret_cast<const uint4*>(aptr[i] + k0);
      *reinterpret_cast<uint4*>(&As[chunk * 8]) = v;
    }
#pragma unroll
    for (int i = 0; i < 8; ++i) {
      int c = i * 256 + tid;
      int rowB = c >> 4, c16 = c & 15;
      size_t off = ((size_t)(nt * BN + rowB)) * kHidden + k0 + c16 * 4;
      float4 v1 = *reinterpret_cast<const float4*>(w1e + off);
      float4 v3 = *reinterpret_cast<const float4*>(w3e + off);
      uint2 p1, p3;
      p1.x = (u32)f2bf(v1.x) | ((u32)f2bf(v1.y) << 16);
      p1.y = (u32)f2bf(v1.z) | ((u32)f2bf(v1.w) << 16);
      p3.x = (u32)f2bf(v3.x) | ((u32)f2bf(v3.y) << 16);
      p3.y = (u32)f2bf(v3.z) | ((u32)f2bf(v3.w) << 16);
      *reinterpret_cast<uint2*>(&B1s[rowB * BK + c16 * 4]) = p1;
      *reinterpret_cast<uint2*>(&B3s[rowB * BK + c16 * 4]) = p3;
    }
    __syncthreads();
#pragma unroll
    for (int kk = 0; kk < 2; ++kk) {
      const int klo = kk * 32 + (lane >> 4) * 8;
      bf16x8 a[4], b1v[4], b3v[4];
#pragma unroll
      for (int m = 0; m < 4; ++m)
        a[m] = *reinterpret_cast<const bf16x8*>(&As[(wr * 64 + m * 16 + (lane & 15)) * BK + klo]);
#pragma unroll
      for (int n = 0; n < 4; ++n) {
        b1v[n] = *reinterpret_cast<const bf16x8*>(&B1s[(wc * 64 + n * 16 + (lane & 15)) * BK + klo]);
        b3v[n] = *reinterpret_cast<const bf16x8*>(&B3s[(wc * 64 + n * 16 + (lane & 15)) * BK + klo]);
      }
#pragma unroll
      for (int m = 0; m < 4; ++m)
#pragma unroll
        for (int n = 0; n < 4; ++n) {
          accG[m][n] = __builtin_amdgcn_mfma_f32_16x16x32_bf16(a[m], b1v[n], accG[m][n], 0, 0, 0);
          accU[m][n] = __builtin_amdgcn_mfma_f32_16x16x32_bf16(a[m], b3v[n], accU[m][n], 0, 0, 0);
        }
    }
    __syncthreads();
  }
#pragma unroll
  for (int m = 0; m < 4; ++m) {
#pragma unroll
    for (int r = 0; r < 4; ++r) {
      int rloc = wr * 64 + m * 16 + ((lane >> 4) * 4) + r;
      int lrow = row0 + rloc;
      if (lrow < ne) {
        size_t base = (size_t)(sb + lrow) * kInter + (size_t)nt * BN + wc * 64 + (lane & 15);
#pragma unroll
        for (int n = 0; n < 4; ++n) {
          float g = accG[m][n][r];
          float u = accU[m][n][r];
          hbuf[base + n * 16] = f2bf((g / (1.f + __expf(-g))) * u);
        }
      }
    }
  }
}

__global__ __launch_bounds__(256, 2) void moe_y_f32(
    const unsigned short* __restrict__ hbuf,
    const float* __restrict__ w2,
    const int* __restrict__ counts, const int* __restrict__ list_idx,
    const float* __restrict__ list_w,
    float* __restrict__ out)
{
  __shared__ unsigned short As[BM * BK];
  __shared__ unsigned short Bs[BN * BK];
  __shared__ int   toks[BM];
  __shared__ float cofs[BM];

  const int tid = threadIdx.x;
  const int nt  = blockIdx.x / MAX_MT;
  const int mt  = blockIdx.x % MAX_MT;

  int e, lm, sb, ne;
  if (!map_tile(counts, mt, e, lm, sb, ne)) return;
  const int row0 = lm * BM;

  if (tid < BM) {
    int lr = row0 + tid;
    bool v = lr < ne;
    toks[tid] = v ? list_idx[e * kTokens + lr] : 0;
    cofs[tid] = v ? list_w [e * kTokens + lr] : 0.f;
  }
  __syncthreads();

  const float* w2e = w2 + (size_t)e * kHidden * kInter;
  const unsigned short* arow = hbuf + (size_t)(sb + row0) * kInter;

  f32x4 acc[4][4];
  const f32x4 zero = {0.f, 0.f, 0.f, 0.f};
#pragma unroll
  for (int m = 0; m < 4; ++m)
#pragma unroll
    for (int n = 0; n < 4; ++n) acc[m][n] = zero;

  const int lane = tid & 63;
  const int wr = (tid >> 6) >> 1;
  const int wc = (tid >> 6) & 1;

  for (int k0 = 0; k0 < kInter; k0 += BK) {
#pragma unroll
    for (int i = 0; i < 4; ++i) {
      int chunk = i * 256 + tid;
      int r = chunk >> 3, c8 = chunk & 7;
      uint4 v = *reinterpret_cast<const uint4*>(arow + (size_t)r * kInter + k0 + c8 * 8);
      *reinterpret_cast<uint4*>(&As[chunk * 8]) = v;
    }
#pragma unroll
    for (int i = 0; i < 8; ++i) {
      int c = i * 256 + tid;
      int rowB = c >> 4, c16 = c & 15;
      size_t off = ((size_t)(nt * BN + rowB)) * kInter + k0 + c16 * 4;
      float4 v2 = *reinterpret_cast<const float4*>(w2e + off);
      uint2 p2;
      p2.x = (u32)f2bf(v2.x) | ((u32)f2bf(v2.y) << 16);
      p2.y = (u32)f2bf(v2.z) | ((u32)f2bf(v2.w) << 16);
      *reinterpret_cast<uint2*>(&Bs[rowB * BK + c16 * 4]) = p2;
    }
    __syncthreads();
#pragma unroll
    for (int kk = 0; kk < 2; ++kk) {
      const int klo = kk * 32 + (lane >> 4) * 8;
      bf16x8 a[4], b[4];
#pragma unroll
      for (int m = 0; m < 4; ++m)
        a[m] = *reinterpret_cast<const bf16x8*>(&As[(wr * 64 + m * 16 + (lane & 15)) * BK + klo]);
#pragma unroll
      for (int n = 0; n < 4; ++n)
        b[n] = *reinterpret_cast<const bf16x8*>(&Bs[(wc * 64 + n * 16 + (lane & 15)) * BK + klo]);
#pragma unroll
      for (int m = 0; m < 4; ++m)
#pragma unroll
        for (int n = 0; n < 4; ++n)
          acc[m][n] = __builtin_amdgcn_mfma_f32_16x16x32_bf16(a[m], b[n], acc[m][n], 0, 0, 0);
    }
    __syncthreads();
  }
#pragma unroll
  for (int m = 0; m < 4; ++m) {
#pragma unroll
    for (int r = 0; r < 4; ++r) {
      int rloc = wr * 64 + m * 16 + ((lane >> 4) * 4) + r;
      if (row0 + rloc < ne) {
        float cf = cofs[rloc];
        size_t obase = (size_t)toks[rloc] * kHidden + (size_t)nt * BN + wc * 64 + (lane & 15);
#pragma unroll
        for (int n = 0; n < 4; ++n)
          atomicAdd(&out[obase + n * 16], cf * acc[m][n][r]);
      }
    }
  }
}

// ---------------------------- host ----------------------------
extern "C" void kernel_launch(void* const* d_in, const int* in_sizes, int n_in,
                              void* d_out, int out_size, void* d_ws, size_t ws_size,
                              hipStream_t stream)
{
  const float* x      = (const float*)d_in[0];
  const float* gate_w = (const float*)d_in[1];
  const float* w1     = (const float*)d_in[2];
  const float* w2     = (const float*)d_in[3];
  const float* w3     = (const float*)d_in[4];
  float* out = (float*)d_out;

  char* ws = (char*)d_ws;
  const size_t MiB = 1ull << 20;
  int*   counts   = (int*)(ws);
  int*   list_idx = (int*)(ws + 1024);
  float* list_w   = (float*)(ws + 1024 + kExperts * kTokens * 4);

  hipMemsetAsync(counts, 0, 1024, stream);
  hipMemsetAsync(out, 0, (size_t)kTokens * kHidden * sizeof(float), stream);

  if (ws_size >= 418 * MiB) {
    unsigned short* xb   = (unsigned short*)(ws + 1 * MiB);
    unsigned short* w1b  = (unsigned short*)(ws + 33 * MiB);
    unsigned short* w3b  = (unsigned short*)(ws + 161 * MiB);
    unsigned short* hbuf = (unsigned short*)(ws + 289 * MiB);
    unsigned short* w2b  = w1b;  // reuse after GU

    const long nch = (long)kExperts * (kInter / BN) * (kHidden / BK) * 1024;
    convert_w<<<4096, 256, 0, stream>>>(w1, w1b, 5, 5, kHidden, nch);
    convert_w<<<4096, 256, 0, stream>>>(w3, w3b, 5, 5, kHidden, nch);
    moe_router<<<kTokens / 4, 256, 0, stream>>>(x, gate_w, xb, counts, list_idx, list_w);
    moe_gu2<<<MAX_MT2 * NPAN_GU, 512, 0, stream>>>(xb, w1b, w3b, counts, list_idx, hbuf);
    convert_w<<<4096, 256, 0, stream>>>(w2, w2b, 4, 6, kInter, nch);
    moe_y2<<<MAX_MT2 * NPAN_Y, 512, 0, stream>>>(hbuf, w2b, counts, list_idx, list_w, out);
  } else {
    unsigned short* xb   = (unsigned short*)(ws + 1 * MiB);
    unsigned short* hbuf = (unsigned short*)(ws + 36 * MiB);
    moe_router<<<kTokens / 4, 256, 0, stream>>>(x, gate_w, xb, counts, list_idx, list_w);
    moe_gu_f32<<<(kInter / BN) * MAX_MT, 256, 0, stream>>>(xb, w1, w3, counts, list_idx, hbuf);
    moe_y_f32 <<<(kHidden / BN) * MAX_MT, 256, 0, stream>>>(hbuf, w2, counts, list_idx, list_w, out);
  }
}

// Round 7
// 1586.951 us; speedup vs baseline: 1.1717x; 1.1717x over previous
//
#include <hip/hip_runtime.h>
#include <stdint.h>
#include <stddef.h>

// ---------------------------------------------------------------------------
// Sparse top-2 MoE, bf16 MFMA, fp32 accumulate.
//   convert: w1/w3/w2 fp32 -> bf16 in MFMA-FRAGMENT order so GEMMs load B
//            operands directly global->register (no LDS for B).
//   router:  logits -> softmax -> top2 -> per-expert compact lists (+x->bf16)
//   GU:      h = silu(x@w1^T) * (x@w3^T)   A-LDS dbuf, B-direct, 1 barrier/tile
//   Y:       out += coef * (h@w2^T)        same structure
// nt-major dispatch (proven r2/3): co-resident blocks share the weight panel
// (L2-hot); A (xb 32MB / hbuf 128MB) re-reads hit L3.
// ws layout (MiB): [0,1) lists | [1,33) xb | [33,161) w1b (later w2b)
//                  [161,289) w3b | [289,418) hbuf
// ---------------------------------------------------------------------------

constexpr int kTokens  = 8192;
constexpr int kHidden  = 2048;
constexpr int kInter   = 4096;
constexpr int kExperts = 8;

constexpr int BM = 128, BN = 128, BK = 64;              // fallback tile
constexpr int MAX_MT = (2 * kTokens) / BM + kExperts;   // 136

constexpr int BM2 = 256, BN2 = 128;                     // main tile
constexpr int MAX_MT2 = (2 * kTokens) / BM2 + kExperts; // 72
constexpr int NT2 = kHidden / BK;                       // 32 K-tiles (GU)
constexpr int NTY = kInter / BK;                        // 64 K-tiles (Y)
constexpr int NPAN_GU = kInter / BN2;                   // 32 B panels
constexpr int NPAN_Y  = kHidden / BN2;                  // 16 B panels
constexpr int kSlotCap = 16512;                         // hbuf rows incl. slack

typedef short bf16x8 __attribute__((ext_vector_type(8)));
typedef float f32x4  __attribute__((ext_vector_type(4)));
typedef unsigned int u32;

__device__ __forceinline__ unsigned short f2bf(float f) {
  union { float f; unsigned u; } v; v.f = f;
  unsigned r = v.u + 0x7FFFu + ((v.u >> 16) & 1u);  // RTNE
  return (unsigned short)(r >> 16);
}

__device__ __forceinline__ void gload16(const void* g, void* l) {
  __builtin_amdgcn_global_load_lds(
      (const __attribute__((address_space(1))) u32*)g,
      (__attribute__((address_space(3))) u32*)l, 16, 0, 0);
}

// ------------------- weight convert: fragment-ordered bf16 -------------------
// dst tile (e, panel p of 128 out-cols, k-tile q of 64): 1024 chunks of 16B.
// chunk c13 = ((g8*2+kk)*64 + l): holds src row g8*16+(l&15), k = (kk*4+(l>>4))*8.
// A B-fragment load in the GEMM is then base + ((g*2+kk)*64 + lane)*16B,
// fully coalesced per wave.
__global__ __launch_bounds__(256) void convert_w_frag(
    const float* __restrict__ src, unsigned short* __restrict__ dst,
    int lp, int lq, int K, long nchunks)
{
  long stride = (long)gridDim.x * blockDim.x;
  for (long g = blockIdx.x * (long)blockDim.x + threadIdx.x; g < nchunks; g += stride) {
    int  c13 = (int)(g & 1023);
    long blk = g >> 10;
    int  q   = (int)(blk & ((1 << lq) - 1));
    long ep  = blk >> lq;
    int  p   = (int)(ep & ((1 << lp) - 1));
    int  e   = (int)(ep >> lp);
    int fg = c13 >> 6, l = c13 & 63;
    int g8 = fg >> 1, kk = fg & 1;
    int row = g8 * 16 + (l & 15);
    int kq  = kk * 4 + (l >> 4);
    size_t soff = (((size_t)(e << lp) + p) * 128 + row) * (size_t)K + (size_t)q * 64 + kq * 8;
    float4 v0 = *reinterpret_cast<const float4*>(src + soff);
    float4 v1 = *reinterpret_cast<const float4*>(src + soff + 4);
    uint4 o;
    o.x = (u32)f2bf(v0.x) | ((u32)f2bf(v0.y) << 16);
    o.y = (u32)f2bf(v0.z) | ((u32)f2bf(v0.w) << 16);
    o.z = (u32)f2bf(v1.x) | ((u32)f2bf(v1.y) << 16);
    o.w = (u32)f2bf(v1.z) | ((u32)f2bf(v1.w) << 16);
    *reinterpret_cast<uint4*>(dst + g * 8) = o;
  }
}

// ---------------------------- router ----------------------------
__global__ __launch_bounds__(256) void moe_router(
    const float* __restrict__ x, const float* __restrict__ gate_w,
    unsigned short* __restrict__ xb, int* __restrict__ counts,
    int* __restrict__ list_idx, float* __restrict__ list_w)
{
  const int lane = threadIdx.x & 63;
  const int wave = threadIdx.x >> 6;
  const int t = blockIdx.x * 4 + wave;

  float acc[kExperts];
#pragma unroll
  for (int e = 0; e < kExperts; ++e) acc[e] = 0.f;

  const float4* xrow = reinterpret_cast<const float4*>(x + (size_t)t * kHidden);
#pragma unroll
  for (int j = 0; j < 8; ++j) {
    float4 xv = xrow[j * 64 + lane];
    uint2 pk;
    pk.x = (u32)f2bf(xv.x) | ((u32)f2bf(xv.y) << 16);
    pk.y = (u32)f2bf(xv.z) | ((u32)f2bf(xv.w) << 16);
    *reinterpret_cast<uint2*>(xb + (size_t)t * kHidden + j * 256 + lane * 4) = pk;
#pragma unroll
    for (int e = 0; e < kExperts; ++e) {
      float4 gv = reinterpret_cast<const float4*>(gate_w + (size_t)e * kHidden)[j * 64 + lane];
      acc[e] += xv.x * gv.x + xv.y * gv.y + xv.z * gv.z + xv.w * gv.w;
    }
  }
#pragma unroll
  for (int e = 0; e < kExperts; ++e) {
#pragma unroll
    for (int m = 32; m >= 1; m >>= 1) acc[e] += __shfl_xor(acc[e], m);
  }
  if (lane == 0) {
    float mx = acc[0];
#pragma unroll
    for (int e = 1; e < kExperts; ++e) mx = fmaxf(mx, acc[e]);
    float p[kExperts]; float s = 0.f;
#pragma unroll
    for (int e = 0; e < kExperts; ++e) { p[e] = __expf(acc[e] - mx); s += p[e]; }
    float inv = 1.f / s;
    int i1 = 0; float v1 = p[0];
#pragma unroll
    for (int e = 1; e < kExperts; ++e) if (p[e] > v1) { v1 = p[e]; i1 = e; }
    int i2 = (i1 == 0) ? 1 : 0; float v2 = p[i2];
#pragma unroll
    for (int e = 0; e < kExperts; ++e) {
      if (e == i1 || e == i2) continue;
      if (p[e] > v2) { v2 = p[e]; i2 = e; }
    }
    int s1 = atomicAdd(&counts[i1], 1);
    list_idx[i1 * kTokens + s1] = t;
    list_w [i1 * kTokens + s1] = v1 * inv;
    int s2 = atomicAdd(&counts[i2], 1);
    list_idx[i2 * kTokens + s2] = t;
    list_w [i2 * kTokens + s2] = v2 * inv;
  }
}

// ------------------- tile mapping helpers -------------------
__device__ __forceinline__ bool map_tile(const int* __restrict__ counts, int mt,
                                         int& e, int& lm, int& sb, int& ne)
{
  int tb = 0; sb = 0;
  for (e = 0; e < kExperts; ++e) {
    ne = counts[e];
    int tiles = (ne + BM - 1) / BM;
    if (mt < tb + tiles) { lm = mt - tb; return true; }
    tb += tiles; sb += ne;
  }
  return false;
}

__device__ __forceinline__ bool map_tile2(const int* __restrict__ counts, int mt,
                                          int& e, int& lm, int& sb, int& ne)
{
  int tb = 0; sb = 0;
  for (e = 0; e < kExperts; ++e) {
    ne = counts[e];
    int tiles = (ne + BM2 - 1) / BM2;
    if (mt < tb + tiles) { lm = mt - tb; return true; }
    tb += tiles; sb += ne;
  }
  return false;
}

// ------------- GU GEMM: A in LDS (dbuf), B direct-to-register -------------
// 8 waves 2wr x 4wc; wave = 128 rows x 32 cols of G and U.
// Per K-tile: issue 4 A-gloads (t+1) | load 8 B-frags (t+1) | 16 a-reads +
// 64 MFMA (compiler-scheduled) | vmcnt(8) forces A | 1 barrier.
__global__ __launch_bounds__(512, 2) void moe_gu3(
    const unsigned short* __restrict__ xb,
    const unsigned short* __restrict__ w1b, const unsigned short* __restrict__ w3b,
    const int* __restrict__ counts, const int* __restrict__ list_idx,
    unsigned short* __restrict__ hbuf)
{
  __shared__ unsigned short As[2][16384];  // 2 x 32 KiB, XOR-swizzled rows
  __shared__ int toks[BM2];

  const int tid = threadIdx.x;
  const int nt  = blockIdx.x / MAX_MT2;   // nt-major: share weight panel in L2
  const int mt  = blockIdx.x % MAX_MT2;

  int e, lm, sb, ne;
  if (!map_tile2(counts, mt, e, lm, sb, ne)) return;
  const int row0 = lm * BM2;

  if (tid < BM2) {
    int lr = row0 + tid;
    toks[tid] = list_idx[e * kTokens + ((lr < ne) ? lr : 0)];
  }
  __syncthreads();

  const int lane = tid & 63;
  const int w    = tid >> 6;
  const int wr   = w >> 2;   // 0..1
  const int wc   = w & 3;    // 0..3

  // A staging sources: 4 chunks/thread, pre-swizzled gather
  const unsigned short* srcA[4];
#pragma unroll
  for (int i = 0; i < 4; ++i) {
    int l = (w * 4 + i) * 64 + lane;
    int r = l >> 3, c = (l & 7) ^ (r & 7);
    srcA[i] = xb + (size_t)toks[r] * kHidden + c * 8;
  }

  // B fragment offsets (elements): frag (n,kk) -> g = wc*2+n
  const size_t tb0 = ((size_t)(e * NPAN_GU + nt)) * NT2 * 8192;
  int foff[2][2];
#pragma unroll
  for (int n = 0; n < 2; ++n)
#pragma unroll
    for (int kk = 0; kk < 2; ++kk)
      foff[n][kk] = (((wc * 2 + n) * 2 + kk) * 64 + lane) * 8;

  f32x4 accG[8][2], accU[8][2];
  const f32x4 zero = {0.f, 0.f, 0.f, 0.f};
#pragma unroll
  for (int m = 0; m < 8; ++m)
#pragma unroll
    for (int n = 0; n < 2; ++n) { accG[m][n] = zero; accU[m][n] = zero; }

  bf16x8 b1a[2][2], b3a[2][2], b1b[2][2], b3b[2][2];

  // prologue: stage A(0) -> As[0]; load B(0) -> a-set
#pragma unroll
  for (int i = 0; i < 4; ++i) gload16(srcA[i], &As[0][(w * 4 + i) * 512]);
  __builtin_amdgcn_sched_barrier(0);
#pragma unroll
  for (int n = 0; n < 2; ++n)
#pragma unroll
    for (int kk = 0; kk < 2; ++kk) {
      b1a[n][kk] = *reinterpret_cast<const bf16x8*>(w1b + tb0 + foff[n][kk]);
      b3a[n][kk] = *reinterpret_cast<const bf16x8*>(w3b + tb0 + foff[n][kk]);
    }
  asm volatile("s_waitcnt vmcnt(8)" ::: "memory");   // forces A(0) (oldest 4)
  __builtin_amdgcn_sched_barrier(0);
  __builtin_amdgcn_s_barrier();

  auto tile = [&](int t, int buf,
                  bf16x8 (&b1c)[2][2], bf16x8 (&b3c)[2][2],
                  bf16x8 (&b1n)[2][2], bf16x8 (&b3n)[2][2]) {
    const int tn = (t + 1 < NT2) ? (t + 1) : (NT2 - 1);
    // 1) issue next A tile (oldest in vmcnt queue)
#pragma unroll
    for (int i = 0; i < 4; ++i)
      gload16(srcA[i] + tn * BK, &As[buf ^ 1][(w * 4 + i) * 512]);
    __builtin_amdgcn_sched_barrier(0);
    // 2) next B frags (compiler handles RAW waits; ~4 phases of cover)
    const size_t tbn = tb0 + (size_t)tn * 8192;
#pragma unroll
    for (int n = 0; n < 2; ++n)
#pragma unroll
      for (int kk = 0; kk < 2; ++kk) {
        b1n[n][kk] = *reinterpret_cast<const bf16x8*>(w1b + tbn + foff[n][kk]);
        b3n[n][kk] = *reinterpret_cast<const bf16x8*>(w3b + tbn + foff[n][kk]);
      }
    // 3) compute: two row-halves; reads + MFMA compiler-interleaved
#pragma unroll
    for (int mh = 0; mh < 2; ++mh) {
      bf16x8 a[4][2];
#pragma unroll
      for (int m = 0; m < 4; ++m) {
        const int r = wr * 128 + mh * 64 + m * 16 + (lane & 15);
#pragma unroll
        for (int kk = 0; kk < 2; ++kk) {
          const int cq = kk * 4 + (lane >> 4);
          a[m][kk] = *reinterpret_cast<const bf16x8*>(
              &As[buf][r * 64 + ((cq ^ (r & 7)) << 3)]);
        }
      }
#pragma unroll
      for (int m = 0; m < 4; ++m)
#pragma unroll
        for (int n = 0; n < 2; ++n)
#pragma unroll
          for (int kk = 0; kk < 2; ++kk) {
            accG[mh * 4 + m][n] = __builtin_amdgcn_mfma_f32_16x16x32_bf16(
                a[m][kk], b1c[n][kk], accG[mh * 4 + m][n], 0, 0, 0);
            accU[mh * 4 + m][n] = __builtin_amdgcn_mfma_f32_16x16x32_bf16(
                a[m][kk], b3c[n][kk], accU[mh * 4 + m][n], 0, 0, 0);
          }
    }
    // 4) force next A staged (leaves the 8 B-loads in flight), sync
    asm volatile("s_waitcnt vmcnt(8)" ::: "memory");
    __builtin_amdgcn_sched_barrier(0);
    __builtin_amdgcn_s_barrier();
  };

  for (int t2 = 0; t2 < NT2; t2 += 2) {
    tile(t2,     0, b1a, b3a, b1b, b3b);
    tile(t2 + 1, 1, b1b, b3b, b1a, b3a);
  }

  // epilogue: h = silu(g)*u
#pragma unroll
  for (int am = 0; am < 8; ++am) {
#pragma unroll
    for (int r = 0; r < 4; ++r) {
      int rloc = wr * 128 + am * 16 + ((lane >> 4) * 4) + r;
      int lrow = row0 + rloc;
      if (lrow < ne) {
        size_t base = (size_t)(sb + lrow) * kInter + (size_t)nt * BN2 + wc * 32 + (lane & 15);
#pragma unroll
        for (int n = 0; n < 2; ++n) {
          float g = accG[am][n][r];
          float u = accU[am][n][r];
          float hv = (g / (1.f + __expf(-g))) * u;
          hbuf[base + n * 16] = f2bf(hv);
        }
      }
    }
  }
}

// ------------- Y GEMM: same structure, 4wr x 2wc (A-redundancy x2) -------------
__global__ __launch_bounds__(512, 2) void moe_y3(
    const unsigned short* __restrict__ hbuf,
    const unsigned short* __restrict__ w2b,
    const int* __restrict__ counts, const int* __restrict__ list_idx,
    const float* __restrict__ list_w,
    float* __restrict__ out)
{
  __shared__ unsigned short As[2][16384];
  __shared__ int   toks[BM2];
  __shared__ float cofs[BM2];

  const int tid = threadIdx.x;
  const int nt  = blockIdx.x / MAX_MT2;
  const int mt  = blockIdx.x % MAX_MT2;

  int e, lm, sb, ne;
  if (!map_tile2(counts, mt, e, lm, sb, ne)) return;
  const int row0 = lm * BM2;

  if (tid < BM2) {
    int lr = row0 + tid;
    bool v = lr < ne;
    toks[tid] = v ? list_idx[e * kTokens + lr] : 0;
    cofs[tid] = v ? list_w [e * kTokens + lr] : 0.f;
  }
  __syncthreads();

  const int lane = tid & 63;
  const int w    = tid >> 6;
  const int wr   = w >> 1;   // 0..3
  const int wc   = w & 1;    // 0..1

  const unsigned short* srcA[4];
#pragma unroll
  for (int i = 0; i < 4; ++i) {
    int l = (w * 4 + i) * 64 + lane;
    int r = l >> 3, c = (l & 7) ^ (r & 7);
    int rg = sb + row0 + r;
    if (rg > kSlotCap - 1) rg = kSlotCap - 1;
    srcA[i] = hbuf + (size_t)rg * kInter + c * 8;
  }

  const size_t tb0 = ((size_t)(e * NPAN_Y + nt)) * NTY * 8192;
  int foff[4][2];
#pragma unroll
  for (int n = 0; n < 4; ++n)
#pragma unroll
    for (int kk = 0; kk < 2; ++kk)
      foff[n][kk] = (((wc * 4 + n) * 2 + kk) * 64 + lane) * 8;

  f32x4 acc[4][4];
  const f32x4 zero = {0.f, 0.f, 0.f, 0.f};
#pragma unroll
  for (int m = 0; m < 4; ++m)
#pragma unroll
    for (int n = 0; n < 4; ++n) acc[m][n] = zero;

  bf16x8 b2a[4][2], b2b[4][2];

#pragma unroll
  for (int i = 0; i < 4; ++i) gload16(srcA[i], &As[0][(w * 4 + i) * 512]);
  __builtin_amdgcn_sched_barrier(0);
#pragma unroll
  for (int n = 0; n < 4; ++n)
#pragma unroll
    for (int kk = 0; kk < 2; ++kk)
      b2a[n][kk] = *reinterpret_cast<const bf16x8*>(w2b + tb0 + foff[n][kk]);
  asm volatile("s_waitcnt vmcnt(8)" ::: "memory");
  __builtin_amdgcn_sched_barrier(0);
  __builtin_amdgcn_s_barrier();

  auto tile = [&](int t, int buf, bf16x8 (&b2c)[4][2], bf16x8 (&b2n)[4][2]) {
    const int tn = (t + 1 < NTY) ? (t + 1) : (NTY - 1);
#pragma unroll
    for (int i = 0; i < 4; ++i)
      gload16(srcA[i] + tn * BK, &As[buf ^ 1][(w * 4 + i) * 512]);
    __builtin_amdgcn_sched_barrier(0);
    const size_t tbn = tb0 + (size_t)tn * 8192;
#pragma unroll
    for (int n = 0; n < 4; ++n)
#pragma unroll
      for (int kk = 0; kk < 2; ++kk)
        b2n[n][kk] = *reinterpret_cast<const bf16x8*>(w2b + tbn + foff[n][kk]);
#pragma unroll
    for (int kk = 0; kk < 2; ++kk) {
      bf16x8 a[4];
#pragma unroll
      for (int m = 0; m < 4; ++m) {
        const int r = wr * 64 + m * 16 + (lane & 15);
        const int cq = kk * 4 + (lane >> 4);
        a[m] = *reinterpret_cast<const bf16x8*>(
            &As[buf][r * 64 + ((cq ^ (r & 7)) << 3)]);
      }
#pragma unroll
      for (int m = 0; m < 4; ++m)
#pragma unroll
        for (int n = 0; n < 4; ++n)
          acc[m][n] = __builtin_amdgcn_mfma_f32_16x16x32_bf16(
              a[m], b2c[n][kk], acc[m][n], 0, 0, 0);
    }
    asm volatile("s_waitcnt vmcnt(8)" ::: "memory");
    __builtin_amdgcn_sched_barrier(0);
    __builtin_amdgcn_s_barrier();
  };

  for (int t2 = 0; t2 < NTY; t2 += 2) {
    tile(t2,     0, b2a, b2b);
    tile(t2 + 1, 1, b2b, b2a);
  }

  // epilogue: out[token] += coef * y
#pragma unroll
  for (int m = 0; m < 4; ++m) {
#pragma unroll
    for (int r = 0; r < 4; ++r) {
      int rloc = wr * 64 + m * 16 + ((lane >> 4) * 4) + r;
      if (row0 + rloc < ne) {
        float cf = cofs[rloc];
        size_t obase = (size_t)toks[rloc] * kHidden + (size_t)nt * BN2 + wc * 64 + (lane & 15);
#pragma unroll
        for (int n = 0; n < 4; ++n)
          atomicAdd(&out[obase + n * 16], cf * acc[m][n][r]);
      }
    }
  }
}

// ===================== fallback (fp32 on-the-fly) ============
__global__ __launch_bounds__(256, 2) void moe_gu_f32(
    const unsigned short* __restrict__ xb,
    const float* __restrict__ w1, const float* __restrict__ w3,
    const int* __restrict__ counts, const int* __restrict__ list_idx,
    unsigned short* __restrict__ hbuf)
{
  __shared__ unsigned short As [BM * BK];
  __shared__ unsigned short B1s[BN * BK];
  __shared__ unsigned short B3s[BN * BK];
  __shared__ int toks[BM];

  const int tid = threadIdx.x;
  const int nt  = blockIdx.x / MAX_MT;
  const int mt  = blockIdx.x % MAX_MT;

  int e, lm, sb, ne;
  if (!map_tile(counts, mt, e, lm, sb, ne)) return;
  const int row0 = lm * BM;

  if (tid < BM) {
    int lr = row0 + tid;
    toks[tid] = list_idx[e * kTokens + ((lr < ne) ? lr : 0)];
  }
  __syncthreads();

  const unsigned short* aptr[4];
#pragma unroll
  for (int i = 0; i < 4; ++i) {
    int chunk = i * 256 + tid;
    int r = chunk >> 3, c8 = chunk & 7;
    aptr[i] = xb + (size_t)toks[r] * kHidden + c8 * 8;
  }
  const float* w1e = w1 + (size_t)e * kInter * kHidden;
  const float* w3e = w3 + (size_t)e * kInter * kHidden;

  f32x4 accG[4][4], accU[4][4];
  const f32x4 zero = {0.f, 0.f, 0.f, 0.f};
#pragma unroll
  for (int m = 0; m < 4; ++m)
#pragma unroll
    for (int n = 0; n < 4; ++n) { accG[m][n] = zero; accU[m][n] = zero; }

  const int lane = tid & 63;
  const int wr = (tid >> 6) >> 1;
  const int wc = (tid >> 6) & 1;

  for (int k0 = 0; k0 < kHidden; k0 += BK) {
#pragma unroll
    for (int i = 0; i < 4; ++i) {
      int chunk = i * 256 + tid;
      uint4 v = *reinterpret_cast<const uint4*>(aptr[i] + k0);
      *reinterpret_cast<uint4*>(&As[chunk * 8]) = v;
    }
#pragma unroll
    for (int i = 0; i < 8; ++i) {
      int c = i * 256 + tid;
      int rowB = c >> 4, c16 = c & 15;
      size_t off = ((size_t)(nt * BN + rowB)) * kHidden + k0 + c16 * 4;
      float4 v1 = *reinterpret_cast<const float4*>(w1e + off);
      float4 v3 = *reinterpret_cast<const float4*>(w3e + off);
      uint2 p1, p3;
      p1.x = (u32)f2bf(v1.x) | ((u32)f2bf(v1.y) << 16);
      p1.y = (u32)f2bf(v1.z) | ((u32)f2bf(v1.w) << 16);
      p3.x = (u32)f2bf(v3.x) | ((u32)f2bf(v3.y) << 16);
      p3.y = (u32)f2bf(v3.z) | ((u32)f2bf(v3.w) << 16);
      *reinterpret_cast<uint2*>(&B1s[rowB * BK + c16 * 4]) = p1;
      *reinterpret_cast<uint2*>(&B3s[rowB * BK + c16 * 4]) = p3;
    }
    __syncthreads();
#pragma unroll
    for (int kk = 0; kk < 2; ++kk) {
      const int klo = kk * 32 + (lane >> 4) * 8;
      bf16x8 a[4], b1v[4], b3v[4];
#pragma unroll
      for (int m = 0; m < 4; ++m)
        a[m] = *reinterpret_cast<const bf16x8*>(&As[(wr * 64 + m * 16 + (lane & 15)) * BK + klo]);
#pragma unroll
      for (int n = 0; n < 4; ++n) {
        b1v[n] = *reinterpret_cast<const bf16x8*>(&B1s[(wc * 64 + n * 16 + (lane & 15)) * BK + klo]);
        b3v[n] = *reinterpret_cast<const bf16x8*>(&B3s[(wc * 64 + n * 16 + (lane & 15)) * BK + klo]);
      }
#pragma unroll
      for (int m = 0; m < 4; ++m)
#pragma unroll
        for (int n = 0; n < 4; ++n) {
          accG[m][n] = __builtin_amdgcn_mfma_f32_16x16x32_bf16(a[m], b1v[n], accG[m][n], 0, 0, 0);
          accU[m][n] = __builtin_amdgcn_mfma_f32_16x16x32_bf16(a[m], b3v[n], accU[m][n], 0, 0, 0);
        }
    }
    __syncthreads();
  }
#pragma unroll
  for (int m = 0; m < 4; ++m) {
#pragma unroll
    for (int r = 0; r < 4; ++r) {
      int rloc = wr * 64 + m * 16 + ((lane >> 4) * 4) + r;
      int lrow = row0 + rloc;
      if (lrow < ne) {
        size_t base = (size_t)(sb + lrow) * kInter + (size_t)nt * BN + wc * 64 + (lane & 15);
#pragma unroll
        for (int n = 0; n < 4; ++n) {
          float g = accG[m][n][r];
          float u = accU[m][n][r];
          hbuf[base + n * 16] = f2bf((g / (1.f + __expf(-g))) * u);
        }
      }
    }
  }
}

__global__ __launch_bounds__(256, 2) void moe_y_f32(
    const unsigned short* __restrict__ hbuf,
    const float* __restrict__ w2,
    const int* __restrict__ counts, const int* __restrict__ list_idx,
    const float* __restrict__ list_w,
    float* __restrict__ out)
{
  __shared__ unsigned short As[BM * BK];
  __shared__ unsigned short Bs[BN * BK];
  __shared__ int   toks[BM];
  __shared__ float cofs[BM];

  const int tid = threadIdx.x;
  const int nt  = blockIdx.x / MAX_MT;
  const int mt  = blockIdx.x % MAX_MT;

  int e, lm, sb, ne;
  if (!map_tile(counts, mt, e, lm, sb, ne)) return;
  const int row0 = lm * BM;

  if (tid < BM) {
    int lr = row0 + tid;
    bool v = lr < ne;
    toks[tid] = v ? list_idx[e * kTokens + lr] : 0;
    cofs[tid] = v ? list_w [e * kTokens + lr] : 0.f;
  }
  __syncthreads();

  const float* w2e = w2 + (size_t)e * kHidden * kInter;
  const unsigned short* arow = hbuf + (size_t)(sb + row0) * kInter;

  f32x4 acc[4][4];
  const f32x4 zero = {0.f, 0.f, 0.f, 0.f};
#pragma unroll
  for (int m = 0; m < 4; ++m)
#pragma unroll
    for (int n = 0; n < 4; ++n) acc[m][n] = zero;

  const int lane = tid & 63;
  const int wr = (tid >> 6) >> 1;
  const int wc = (tid >> 6) & 1;

  for (int k0 = 0; k0 < kInter; k0 += BK) {
#pragma unroll
    for (int i = 0; i < 4; ++i) {
      int chunk = i * 256 + tid;
      int r = chunk >> 3, c8 = chunk & 7;
      uint4 v = *reinterpret_cast<const uint4*>(arow + (size_t)r * kInter + k0 + c8 * 8);
      *reinterpret_cast<uint4*>(&As[chunk * 8]) = v;
    }
#pragma unroll
    for (int i = 0; i < 8; ++i) {
      int c = i * 256 + tid;
      int rowB = c >> 4, c16 = c & 15;
      size_t off = ((size_t)(nt * BN + rowB)) * kInter + k0 + c16 * 4;
      float4 v2 = *reinterpret_cast<const float4*>(w2e + off);
      uint2 p2;
      p2.x = (u32)f2bf(v2.x) | ((u32)f2bf(v2.y) << 16);
      p2.y = (u32)f2bf(v2.z) | ((u32)f2bf(v2.w) << 16);
      *reinterpret_cast<uint2*>(&Bs[rowB * BK + c16 * 4]) = p2;
    }
    __syncthreads();
#pragma unroll
    for (int kk = 0; kk < 2; ++kk) {
      const int klo = kk * 32 + (lane >> 4) * 8;
      bf16x8 a[4], b[4];
#pragma unroll
      for (int m = 0; m < 4; ++m)
        a[m] = *reinterpret_cast<const bf16x8*>(&As[(wr * 64 + m * 16 + (lane & 15)) * BK + klo]);
#pragma unroll
      for (int n = 0; n < 4; ++n)
        b[n] = *reinterpret_cast<const bf16x8*>(&Bs[(wc * 64 + n * 16 + (lane & 15)) * BK + klo]);
#pragma unroll
      for (int m = 0; m < 4; ++m)
#pragma unroll
        for (int n = 0; n < 4; ++n)
          acc[m][n] = __builtin_amdgcn_mfma_f32_16x16x32_bf16(a[m], b[n], acc[m][n], 0, 0, 0);
    }
    __syncthreads();
  }
#pragma unroll
  for (int m = 0; m < 4; ++m) {
#pragma unroll
    for (int r = 0; r < 4; ++r) {
      int rloc = wr * 64 + m * 16 + ((lane >> 4) * 4) + r;
      if (row0 + rloc < ne) {
        float cf = cofs[rloc];
        size_t obase = (size_t)toks[rloc] * kHidden + (size_t)nt * BN + wc * 64 + (lane & 15);
#pragma unroll
        for (int n = 0; n < 4; ++n)
          atomicAdd(&out[obase + n * 16], cf * acc[m][n][r]);
      }
    }
  }
}

// ---------------------------- host ----------------------------
extern "C" void kernel_launch(void* const* d_in, const int* in_sizes, int n_in,
                              void* d_out, int out_size, void* d_ws, size_t ws_size,
                              hipStream_t stream)
{
  const float* x      = (const float*)d_in[0];
  const float* gate_w = (const float*)d_in[1];
  const float* w1     = (const float*)d_in[2];
  const float* w2     = (const float*)d_in[3];
  const float* w3     = (const float*)d_in[4];
  float* out = (float*)d_out;

  char* ws = (char*)d_ws;
  const size_t MiB = 1ull << 20;
  int*   counts   = (int*)(ws);
  int*   list_idx = (int*)(ws + 1024);
  float* list_w   = (float*)(ws + 1024 + kExperts * kTokens * 4);

  hipMemsetAsync(counts, 0, 1024, stream);
  hipMemsetAsync(out, 0, (size_t)kTokens * kHidden * sizeof(float), stream);

  if (ws_size >= 418 * MiB) {
    unsigned short* xb   = (unsigned short*)(ws + 1 * MiB);
    unsigned short* w1b  = (unsigned short*)(ws + 33 * MiB);
    unsigned short* w3b  = (unsigned short*)(ws + 161 * MiB);
    unsigned short* hbuf = (unsigned short*)(ws + 289 * MiB);
    unsigned short* w2b  = w1b;  // reuse after GU

    const long nch = (long)kExperts * NPAN_GU * NT2 * 1024;  // == w2's count
    convert_w_frag<<<4096, 256, 0, stream>>>(w1, w1b, 5, 5, kHidden, nch);
    convert_w_frag<<<4096, 256, 0, stream>>>(w3, w3b, 5, 5, kHidden, nch);
    moe_router<<<kTokens / 4, 256, 0, stream>>>(x, gate_w, xb, counts, list_idx, list_w);
    moe_gu3<<<NPAN_GU * MAX_MT2, 512, 0, stream>>>(xb, w1b, w3b, counts, list_idx, hbuf);
    convert_w_frag<<<4096, 256, 0, stream>>>(w2, w2b, 4, 6, kInter, nch);
    moe_y3<<<NPAN_Y * MAX_MT2, 512, 0, stream>>>(hbuf, w2b, counts, list_idx, list_w, out);
  } else {
    unsigned short* xb   = (unsigned short*)(ws + 1 * MiB);
    unsigned short* hbuf = (unsigned short*)(ws + 36 * MiB);
    moe_router<<<kTokens / 4, 256, 0, stream>>>(x, gate_w, xb, counts, list_idx, list_w);
    moe_gu_f32<<<(kInter / BN) * MAX_MT, 256, 0, stream>>>(xb, w1, w3, counts, list_idx, hbuf);
    moe_y_f32 <<<(kHidden / BN) * MAX_MT, 256, 0, stream>>>(hbuf, w2, counts, list_idx, list_w, out);
  }
}